// Round 7
// baseline (781.349 us; speedup 1.0000x reference)
//
#include <hip/hip_runtime.h>
#include <cfloat>
#include <cstddef>

// VQ-VAE vector quantizer, MI355X / gfx950 — R7: GEMM register tiling.
//
// R3/R5/R6 evidence: any structure keeping a large read-only z-fragment live
// across the code loop gets rematerialized/AGPR-parked by the allocator
// (VGPR_Count 40/32, VALU issue 2-3.4x the 27us FMA floor). Fix: keep only
// ACCUMULATORS resident (RMW every iter -> unspillable). Each lane owns an
// 8-row x 8-code fp32 acc tile; z streams from LDS (transposed, b128,
// broadcast), e streams from global (L2-resident), double-buffered in regs.
//
// Argmin numerics (bit-exact rounds 2/3/5/6): d_j = fl32(fl32(z2+e2_j)-2*dot),
// z2/e2 double-accumulated then rounded once; dot = fp32 fma chain (assoc
// free: error << ulp(64) grid that dominates); global first-index tie-break
// via lexicographic (d,j) merges.

#define NROWS 32768
#define NE    1024
#define EDIM  64
#define RPB   64
#define NBLK  (NROWS / RPB)   // 512
#define TPB   256             // 4 waves

#define OFF_LOSS ((size_t)0)
#define OFF_ZQ   ((size_t)1)
#define OFF_PERP ((size_t)2097153)
#define OFF_OH   ((size_t)2097154)
#define OFF_IDX  ((size_t)35651586)

typedef float f2_t __attribute__((ext_vector_type(2)));

// ws: [0,4096) int hist[1024]; [4096,6144) float partial[512]

__global__ __launch_bounds__(TPB, 2) void vq_main(const float* __restrict__ z,
                                                  const float* __restrict__ emb,
                                                  int* __restrict__ hist,
                                                  float* __restrict__ partial,
                                                  float* __restrict__ out) {
    const int t    = threadIdx.x;
    const int lane = t & 63;
    const int w    = t >> 6;        // wave 0..3
    const int rg   = lane >> 3;     // row group 0..7
    const int cg   = lane & 7;      // code group 0..7
    const int rb   = rg << 3;       // lane's first local row
    const int r0   = blockIdx.x * RPB;
    const int bb   = r0 >> 10;      // batch image (64 | 1024 -> single b per block)
    const int m0   = r0 & 1023;

    __shared__ float s_zT[64][64];  // [k][row], reads broadcast/2-way -> free
    __shared__ float s_e2[NE];
    __shared__ float s_z2[64];
    __shared__ float s_wd[4][64];
    __shared__ int   s_wj[4][64];
    __shared__ int   s_idx[64];
    __shared__ float s_l[4];

    // ---- stage zT: thread t loads 16 floats of channel k=t>>2 (coalesced) --
    {
        const int k = t >> 2, mg = t & 3;
        const float* src = z + (size_t)bb * 65536 + (size_t)k * 1024 + (m0 + mg * 16);
        float* dst = &s_zT[k][mg * 16];
#pragma unroll
        for (int i = 0; i < 4; ++i)
            ((float4*)dst)[i] = ((const float4*)src)[i];
    }
    // ---- e2: 4 codes per thread, double-accumulated, single fp32 rounding --
#pragma unroll
    for (int i = 0; i < 4; ++i) {
        const int j = t + 256 * i;
        const float4* e4 = (const float4*)(emb + ((size_t)j << 6));
        double s = 0.0;
#pragma unroll
        for (int k = 0; k < 16; ++k) {
            float4 v = e4[k];
            s += (double)v.x * (double)v.x; s += (double)v.y * (double)v.y;
            s += (double)v.z * (double)v.z; s += (double)v.w * (double)v.w;
        }
        s_e2[j] = (float)s;
    }
    __syncthreads();
    // ---- z2 per row (ascending k == ascending channels, as rounds 2-6) ----
    if (t < 64) {
        double s = 0.0;
        for (int k = 0; k < 64; ++k) {
            float v = s_zT[k][t];
            s += (double)v * (double)v;
        }
        s_z2[t] = (float)s;
    }
    __syncthreads();

    f2_t z2p[4];
#pragma unroll
    for (int rq = 0; rq < 4; ++rq) {
        z2p[rq][0] = s_z2[rb + 2 * rq];
        z2p[rq][1] = s_z2[rb + 2 * rq + 1];
    }

    float bd[8]; int bj[8];
#pragma unroll
    for (int i = 0; i < 8; ++i) { bd[i] = FLT_MAX; bj[i] = NE; }

    // ---- 4 chunks per wave: chunk = 4*cidx + w, 64 codes each ----
    for (int cidx = 0; cidx < 4; ++cidx) {
        const int c0 = ((cidx * 4 + w) << 6) + (cg << 3);  // lane's 8 codes
        f2_t acc[8][4];                                     // [code][rowpair]
#pragma unroll
        for (int c = 0; c < 8; ++c)
#pragma unroll
            for (int rq = 0; rq < 4; ++rq) acc[c][rq] = (f2_t)(0.f);

        auto fma_group = [&](const float4 (&ef)[8], int kbase) {
#pragma unroll
            for (int kk = 0; kk < 4; ++kk) {
                const int k = kbase + kk;
                const float4 zlo = *(const float4*)&s_zT[k][rb];
                const float4 zhi = *(const float4*)&s_zT[k][rb + 4];
                f2_t zp[4];
                zp[0][0] = zlo.x; zp[0][1] = zlo.y;
                zp[1][0] = zlo.z; zp[1][1] = zlo.w;
                zp[2][0] = zhi.x; zp[2][1] = zhi.y;
                zp[3][0] = zhi.z; zp[3][1] = zhi.w;
#pragma unroll
                for (int c = 0; c < 8; ++c) {
                    const float sc = (&ef[c].x)[kk];
                    const f2_t sv = {sc, sc};
#pragma unroll
                    for (int rq = 0; rq < 4; ++rq)
                        acc[c][rq] = __builtin_elementwise_fma(zp[rq], sv, acc[c][rq]);
                }
            }
        };

        float4 ef0[8], ef1[8];
#pragma unroll
        for (int c = 0; c < 8; ++c)
            ef0[c] = *(const float4*)(emb + ((size_t)(c0 + c) << 6));

#pragma unroll 1
        for (int k4 = 0; k4 < 16; k4 += 2) {
#pragma unroll
            for (int c = 0; c < 8; ++c)
                ef1[c] = *(const float4*)(emb + ((size_t)(c0 + c) << 6) + ((k4 + 1) << 2));
            fma_group(ef0, k4 << 2);
#pragma unroll
            for (int c = 0; c < 8; ++c)   // &15 wrap avoids OOB on last iter
                ef0[c] = *(const float4*)(emb + ((size_t)(c0 + c) << 6) + (((k4 + 2) & 15) << 2));
            fma_group(ef1, (k4 + 1) << 2);
        }

        // ---- d-transform + per-row argmin (ascending j -> strict < ) ----
#pragma unroll
        for (int c = 0; c < 8; ++c) {
            const float e2c = s_e2[c0 + c];
            const int   j   = c0 + c;
#pragma unroll
            for (int rq = 0; rq < 4; ++rq) {
                f2_t d = (z2p[rq] + e2c) - 2.0f * acc[c][rq];
                if (d[0] < bd[2 * rq])     { bd[2 * rq]     = d[0]; bj[2 * rq]     = j; }
                if (d[1] < bd[2 * rq + 1]) { bd[2 * rq + 1] = d[1]; bj[2 * rq + 1] = j; }
            }
        }
    }

    // ---- butterfly over the 8 cg-lanes (lexicographic (d,j)) ----
#pragma unroll
    for (int mask = 1; mask < 8; mask <<= 1) {
#pragma unroll
        for (int i = 0; i < 8; ++i) {
            float od = __shfl_xor(bd[i], mask);
            int   oj = __shfl_xor(bj[i], mask);
            if (od < bd[i] || (od == bd[i] && oj < bj[i])) { bd[i] = od; bj[i] = oj; }
        }
    }
    if (cg == 0) {
#pragma unroll
        for (int i = 0; i < 8; ++i) { s_wd[w][rb + i] = bd[i]; s_wj[w][rb + i] = bj[i]; }
    }
    __syncthreads();

    // ---- cross-wave merge, index write, histogram ----
    if (t < 64) {
        float bdd = s_wd[0][t]; int bjj = s_wj[0][t];
#pragma unroll
        for (int ww = 1; ww < 4; ++ww) {
            float dw = s_wd[ww][t]; int jw = s_wj[ww][t];
            if (dw < bdd || (dw == bdd && jw < bjj)) { bdd = dw; bjj = jw; }
        }
        s_idx[t] = bjj;
        out[OFF_IDX + (size_t)(r0 + t)] = (float)bjj;
        atomicAdd(&hist[bjj], 1);
    }
    __syncthreads();

    // ---- z_q (straight-through) + loss partial ----
    const size_t zbE = (size_t)bb * 65536 + (size_t)(m0 + lane);
    const int    jjx = s_idx[lane];
    const float* er  = emb + ((size_t)jjx << 6);
    float* zq = out + OFF_ZQ + zbE;
    float lsum = 0.f;
#pragma unroll
    for (int c = w; c < EDIM; c += 4) {
        float zc   = s_zT[c][lane];                 // LDS, bank-free
        float ev   = er[c];                         // gather (L2-hot)
        float diff = ev - zc;
        zq[(size_t)c * 1024] = zc + diff;           // mimic zp + (z_q - zp)
        lsum = fmaf(diff, diff, lsum);
    }
#pragma unroll
    for (int off = 32; off >= 1; off >>= 1) lsum += __shfl_down(lsum, off);
    if (lane == 0) s_l[w] = lsum;
    __syncthreads();
    if (t == 0)
        partial[blockIdx.x] = (s_l[0] + s_l[1]) + (s_l[2] + s_l[3]);

    // ---- one-hot: 64 rows x 1024 cols, nontemporal 8B stores ----
    float* oh = out + OFF_OH;
    for (int mm = 0; mm < RPB; ++mm) {
        const int jr = s_idx[mm];
        float* rowp = oh + (size_t)(r0 + mm) * 1024;
        f2_t v0 = (f2_t)(0.f);
        if ((jr >> 1) == t) v0[jr & 1] = 1.0f;
        __builtin_nontemporal_store(v0, (f2_t*)rowp + t);        // cols [2t,2t+1]
        f2_t v1 = (f2_t)(0.f);
        if ((jr >> 1) == t + 256) v1[jr & 1] = 1.0f;
        __builtin_nontemporal_store(v1, (f2_t*)rowp + t + 256);  // cols [512+2t,..]
    }
}

__global__ __launch_bounds__(1024) void vq_final(const int* __restrict__ hist,
                                                 const float* __restrict__ partial,
                                                 float* __restrict__ out) {
    const int t = threadIdx.x;
    float p    = (float)hist[t] * (1.0f / 32768.0f);
    float term = p * logf(p + 1e-10f);
    float lp   = (t < NBLK) ? partial[t] : 0.f;
#pragma unroll
    for (int off = 32; off >= 1; off >>= 1) {
        term += __shfl_down(term, off);
        lp   += __shfl_down(lp, off);
    }
    __shared__ float st[16], sl[16];
    int ww = t >> 6, ln = t & 63;
    if (ln == 0) { st[ww] = term; sl[ww] = lp; }
    __syncthreads();
    if (t == 0) {
        float s = 0.f, l = 0.f;
#pragma unroll
        for (int i = 0; i < 16; ++i) { s += st[i]; l += sl[i]; }
        out[OFF_LOSS] = 1.25f * l * (1.0f / 2097152.0f);  // (1+beta)*mean
        out[OFF_PERP] = expf(-s);
    }
}

extern "C" void kernel_launch(void* const* d_in, const int* in_sizes, int n_in,
                              void* d_out, int out_size, void* d_ws, size_t ws_size,
                              hipStream_t stream) {
    const float* z   = (const float*)d_in[0];
    const float* emb = (const float*)d_in[1];
    float* out     = (float*)d_out;
    int*   hist    = (int*)d_ws;
    float* partial = (float*)((char*)d_ws + 4096);

    hipMemsetAsync(hist, 0, 4096, stream);
    vq_main<<<NBLK, TPB, 0, stream>>>(z, emb, hist, partial, out);
    vq_final<<<1, 1024, 0, stream>>>(hist, partial, out);
}

// Round 8
// 306.429 us; speedup vs baseline: 2.5499x; 2.5499x over previous
//
#include <hip/hip_runtime.h>
#include <cfloat>
#include <cstddef>

// VQ-VAE vector quantizer, MI355X / gfx950 — R8.
//
// R7 lesson: per-lane codebook gathers (128MB of L2-missable reads) thrashed
// L2 -> one-hot NT lines evicted mid-assembly -> 9x HBM write amplification
// (WRITE 1.26GB, FETCH 161MB). R8 keeps R7's resident-accumulator insight
// but restores WAVE-UNIFORM codebook access (scalar K$ path, as R3-R6 where
// FETCH was 5MB): lane = row, wave-uniform 16-code groups, e-values as SGPR
// FMA operands; z streamed from LDS transposed (b32, 2-way bank = free).
//
// Argmin numerics (bit-exact rounds 2/3/5/6/7): d_j = fl32(fl32(z2+e2_j)-2dot),
// z2/e2 double-accumulated then rounded once; dot = fp32 fma chain (assoc
// free: error << ulp(64) grid); ascending-j strict < in-lane, lexicographic
// (d,j) cross-wave merge -> np.argmin first-index tie-break.

#define NROWS 32768
#define NE    1024
#define EDIM  64
#define RPB   64
#define NBLK  (NROWS / RPB)   // 512
#define TPB   256             // 4 waves

#define OFF_LOSS ((size_t)0)
#define OFF_ZQ   ((size_t)1)
#define OFF_PERP ((size_t)2097153)
#define OFF_OH   ((size_t)2097154)
#define OFF_IDX  ((size_t)35651586)

typedef float f2_t __attribute__((ext_vector_type(2)));

// ws: [0,4096) int hist[1024]; [4096,6144) float partial[512]

__global__ __launch_bounds__(TPB, 2) void vq_main(const float* __restrict__ z,
                                                  const float* __restrict__ emb,
                                                  int* __restrict__ hist,
                                                  float* __restrict__ partial,
                                                  float* __restrict__ out) {
    const int t    = threadIdx.x;
    const int lane = t & 63;
    const int w    = t >> 6;        // wave 0..3
    const int r0   = blockIdx.x * RPB;
    const int bb   = r0 >> 10;      // 64 | 1024 -> one image per block
    const int m0   = r0 & 1023;

    __shared__ float s_zT[64][64];  // [k][row], 16KB; b32 reads 2-way = free
    __shared__ float s_e2[NE];
    __shared__ float s_z2[64];
    __shared__ float s_wd[4][64];
    __shared__ int   s_wj[4][64];
    __shared__ int   s_idx[64];
    __shared__ float s_l[4];

    // ---- stage zT: thread t loads 16 floats of channel k=t>>2 (coalesced) --
    {
        const int k = t >> 2, mg = t & 3;
        const float* src = z + (size_t)bb * 65536 + (size_t)k * 1024 + (m0 + mg * 16);
        float* dst = &s_zT[k][mg * 16];
#pragma unroll
        for (int i = 0; i < 4; ++i)
            ((float4*)dst)[i] = ((const float4*)src)[i];
    }
    // ---- e2: 4 codes/thread, double-accumulated, single fp32 rounding ----
#pragma unroll
    for (int i = 0; i < 4; ++i) {
        const int j = t + 256 * i;
        const float4* e4 = (const float4*)(emb + ((size_t)j << 6));
        double s = 0.0;
#pragma unroll
        for (int k = 0; k < 16; ++k) {
            float4 v = e4[k];
            s += (double)v.x * (double)v.x; s += (double)v.y * (double)v.y;
            s += (double)v.z * (double)v.z; s += (double)v.w * (double)v.w;
        }
        s_e2[j] = (float)s;
    }
    __syncthreads();
    // ---- z2 per row (ascending k, double, single rounding) ----
    if (t < 64) {
        double s = 0.0;
        for (int k = 0; k < 64; ++k) {
            float v = s_zT[k][t];
            s += (double)v * (double)v;
        }
        s_z2[t] = (float)s;
    }
    __syncthreads();

    const float z2f = s_z2[lane];   // lane = row
    float bd = FLT_MAX;
    int   bj = NE;

    // ---- 16 passes x 16 wave-uniform codes; accs RMW -> unspillable ----
#pragma unroll 1
    for (int p = 0; p < 16; ++p) {
        const int cbase = __builtin_amdgcn_readfirstlane((p * 4 + w) << 4);
        const float* ep = emb + ((size_t)cbase << 6);   // uniform pointer
        float acc[16];
#pragma unroll
        for (int c = 0; c < 16; ++c) acc[c] = 0.f;

#pragma unroll 2
        for (int k4 = 0; k4 < 16; ++k4) {
            const int k0 = k4 << 2;
            const float zf0 = s_zT[k0 + 0][lane];
            const float zf1 = s_zT[k0 + 1][lane];
            const float zf2 = s_zT[k0 + 2][lane];
            const float zf3 = s_zT[k0 + 3][lane];
#pragma unroll
            for (int c = 0; c < 16; ++c) {
                const float* ec = ep + (c << 6) + k0;   // uniform -> s_load
                acc[c] = fmaf(ec[0], zf0, acc[c]);
                acc[c] = fmaf(ec[1], zf1, acc[c]);
                acc[c] = fmaf(ec[2], zf2, acc[c]);
                acc[c] = fmaf(ec[3], zf3, acc[c]);
            }
        }
        // ---- d-transform + argmin (ascending j -> strict <) ----
#pragma unroll
        for (int c = 0; c < 16; ++c) {
            const int   j = cbase + c;
            const float d = (z2f + s_e2[j]) - 2.0f * acc[c];
            if (d < bd) { bd = d; bj = j; }
        }
    }

    // ---- cross-wave merge (lexicographic (d,j)), idx write, histogram ----
    s_wd[w][lane] = bd;
    s_wj[w][lane] = bj;
    __syncthreads();
    if (t < 64) {
        float bdd = s_wd[0][t]; int bjj = s_wj[0][t];
#pragma unroll
        for (int ww = 1; ww < 4; ++ww) {
            float dw = s_wd[ww][t]; int jw = s_wj[ww][t];
            if (dw < bdd || (dw == bdd && jw < bjj)) { bdd = dw; bjj = jw; }
        }
        s_idx[t] = bjj;
        out[OFF_IDX + (size_t)(r0 + t)] = (float)bjj;
        atomicAdd(&hist[bjj], 1);
    }
    __syncthreads();

    // ---- z_q (straight-through) + loss partial ----
    const size_t zbE = (size_t)bb * 65536 + (size_t)(m0 + lane);
    const int    jjx = s_idx[lane];
    const float* er  = emb + ((size_t)jjx << 6);
    float* zq = out + OFF_ZQ + zbE;
    float lsum = 0.f;
#pragma unroll
    for (int c = w; c < EDIM; c += 4) {
        float zc   = s_zT[c][lane];                 // LDS, 2-way free
        float ev   = er[c];                         // gather (L1/L2-hot)
        float diff = ev - zc;
        zq[(size_t)c * 1024] = zc + diff;           // mimic zp + (z_q - zp)
        lsum = fmaf(diff, diff, lsum);
    }
#pragma unroll
    for (int off = 32; off >= 1; off >>= 1) lsum += __shfl_down(lsum, off);
    if (lane == 0) s_l[w] = lsum;
    __syncthreads();
    if (t == 0)
        partial[blockIdx.x] = (s_l[0] + s_l[1]) + (s_l[2] + s_l[3]);

    // ---- one-hot: 64 rows x 1024 cols, nontemporal 8B stores ----
    float* oh = out + OFF_OH;
    for (int mm = 0; mm < RPB; ++mm) {
        const int jr = s_idx[mm];
        float* rowp = oh + (size_t)(r0 + mm) * 1024;
        f2_t v0 = (f2_t)(0.f);
        if ((jr >> 1) == t) v0[jr & 1] = 1.0f;
        __builtin_nontemporal_store(v0, (f2_t*)rowp + t);        // cols [2t,2t+1]
        f2_t v1 = (f2_t)(0.f);
        if ((jr >> 1) == t + 256) v1[jr & 1] = 1.0f;
        __builtin_nontemporal_store(v1, (f2_t*)rowp + t + 256);  // cols [512+2t,..]
    }
}

__global__ __launch_bounds__(1024) void vq_final(const int* __restrict__ hist,
                                                 const float* __restrict__ partial,
                                                 float* __restrict__ out) {
    const int t = threadIdx.x;
    float p    = (float)hist[t] * (1.0f / 32768.0f);
    float term = p * logf(p + 1e-10f);
    float lp   = (t < NBLK) ? partial[t] : 0.f;
#pragma unroll
    for (int off = 32; off >= 1; off >>= 1) {
        term += __shfl_down(term, off);
        lp   += __shfl_down(lp, off);
    }
    __shared__ float st[16], sl[16];
    int ww = t >> 6, ln = t & 63;
    if (ln == 0) { st[ww] = term; sl[ww] = lp; }
    __syncthreads();
    if (t == 0) {
        float s = 0.f, l = 0.f;
#pragma unroll
        for (int i = 0; i < 16; ++i) { s += st[i]; l += sl[i]; }
        out[OFF_LOSS] = 1.25f * l * (1.0f / 2097152.0f);  // (1+beta)*mean
        out[OFF_PERP] = expf(-s);
    }
}

extern "C" void kernel_launch(void* const* d_in, const int* in_sizes, int n_in,
                              void* d_out, int out_size, void* d_ws, size_t ws_size,
                              hipStream_t stream) {
    const float* z   = (const float*)d_in[0];
    const float* emb = (const float*)d_in[1];
    float* out     = (float*)d_out;
    int*   hist    = (int*)d_ws;
    float* partial = (float*)((char*)d_ws + 4096);

    hipMemsetAsync(hist, 0, 4096, stream);
    vq_main<<<NBLK, TPB, 0, stream>>>(z, emb, hist, partial, out);
    vq_final<<<1, 1024, 0, stream>>>(hist, partial, out);
}